// Round 5
// baseline (550.578 us; speedup 1.0000x reference)
//
#include <hip/hip_runtime.h>
#include <stdint.h>
#include <math.h>

// ---------------------------------------------------------------------------
// MultiheadSdpaDiff3 round 5.
// ws layout (bytes):
//   xb   @ 0          : 16777216   (x as bf16 [4096][2048])
//   Wtq  @ 16777216   : 8388608    (Wq^T bf16 [N][K])
//   Wtk  @ 25165824   : 8388608    (contiguous after Wtq -> merged QK gemm)
//   Wtv  @ 33554432   : 8388608
//   Wto  @ 41943040   : 8388608
//   QKb  @ 50331648   : 33554432   (bf16 [4096][4096]: cols 0-2047 Q, 2048-4095 K)
//   Vt   @ 83886080   : 16777216   (bf16 [2048 e][4096 bt] = V^T, from gemm)
//   o12b @ 100663296  : 33554432   (bf16 [c][bt][h*256+e])
//   ob   @ 134217728  : 16777216   (combined+rmsnormed bf16 [4096][2048])
//   lam  @ 150994944  : 256
// ---------------------------------------------------------------------------

typedef unsigned short u16;
typedef short bf16x8 __attribute__((ext_vector_type(8)));
typedef float f32x4 __attribute__((ext_vector_type(4)));

typedef uint32_t __attribute__((address_space(1))) as1_u32;
typedef uint32_t __attribute__((address_space(3))) as3_u32;

#define LAMBDA_INIT 0.78360576653162453f

__device__ __forceinline__ u16 f2bf(float f) {
  uint32_t u = __float_as_uint(f);
  u += 0x7FFFu + ((u >> 16) & 1u);   // RNE
  return (u16)(u >> 16);
}
__device__ __forceinline__ float bf2f(u16 v) {
  return __uint_as_float(((uint32_t)v) << 16);
}

__device__ __forceinline__ void async16(u16* lds, const u16* g) {
  __builtin_amdgcn_global_load_lds((const as1_u32*)(uintptr_t)g,
                                   (as3_u32*)(uint32_t)(uintptr_t)lds, 16, 0, 0);
}

__device__ __forceinline__ f32x4 mfma16(bf16x8 a, bf16x8 b, f32x4 c) {
  return __builtin_amdgcn_mfma_f32_16x16x32_bf16(a, b, c, 0, 0, 0);
}

// --------------------------- prep kernels ----------------------------------

__global__ void cast_x_kernel(const float* __restrict__ x, u16* __restrict__ xb, int n4) {
  int i = blockIdx.x * 256 + threadIdx.x;
  if (i < n4) {
    float4 v = ((const float4*)x)[i];
    ushort4 o;
    o.x = f2bf(v.x); o.y = f2bf(v.y); o.z = f2bf(v.z); o.w = f2bf(v.w);
    ((ushort4*)xb)[i] = o;
  }
}

// Wt[n][k] = bf16(W[k][n]); 4 matrices in one launch (z selects).
__global__ void transpose_w_kernel(const float* __restrict__ W0, const float* __restrict__ W1,
                                   const float* __restrict__ W2, const float* __restrict__ W3,
                                   u16* __restrict__ D0, u16* __restrict__ D1,
                                   u16* __restrict__ D2, u16* __restrict__ D3) {
  __shared__ float tile[32][33];
  int z = blockIdx.z;
  const float* W = (z == 0) ? W0 : (z == 1) ? W1 : (z == 2) ? W2 : W3;
  u16* Wt = (z == 0) ? D0 : (z == 1) ? D1 : (z == 2) ? D2 : D3;
  int tx = threadIdx.x, ty = threadIdx.y;
  int c0 = blockIdx.x * 32, r0 = blockIdx.y * 32;
#pragma unroll
  for (int i = 0; i < 32; i += 8)
    tile[ty + i][tx] = W[(size_t)(r0 + ty + i) * 2048 + c0 + tx];
  __syncthreads();
#pragma unroll
  for (int i = 0; i < 32; i += 8)
    Wt[(size_t)(c0 + ty + i) * 2048 + r0 + tx] = f2bf(tile[tx][ty + i]);
}

__global__ void lam_kernel(const float* __restrict__ lq1, const float* __restrict__ lk1,
                           const float* __restrict__ lq2, const float* __restrict__ lk2,
                           float* __restrict__ out) {
  int L = threadIdx.x;  // 64 threads
  float d1 = lq1[L] * lk1[L] + lq1[L + 64] * lk1[L + 64];
  float d2 = lq2[L] * lk2[L] + lq2[L + 64] * lk2[L + 64];
#pragma unroll
  for (int m = 1; m < 64; m <<= 1) {
    d1 += __shfl_xor(d1, m);
    d2 += __shfl_xor(d2, m);
  }
  if (L == 0) out[0] = __expf(d1) - __expf(d2) + LAMBDA_INIT;
}

// --------------------------- GEMM (m97 structure) --------------------------
template <int OUT_BF16>
__global__ __launch_bounds__(256, 2) void gemm_bt_kernel(const u16* __restrict__ A,
                                                         const u16* __restrict__ Bt,
                                                         void* __restrict__ Cout,
                                                         int M, int N, int K) {
  __shared__ __attribute__((aligned(16))) u16 As[128 * 32];
  __shared__ __attribute__((aligned(16))) u16 Bs[128 * 32];
  int t = threadIdx.x;
  int lane = t & 63, w = t >> 6;
  int lr = lane & 15, lq = lane >> 4;
  int m0 = blockIdx.y * 128, n0 = blockIdx.x * 128;
  int wm = (w >> 1) * 64, wn = (w & 1) * 64;
  const u16* Ab = A + (size_t)m0 * K;
  const u16* Bb = Bt + (size_t)n0 * K;
  f32x4 acc[4][4] = {};
  int r0 = t >> 2;
  int kc0 = (t & 3) * 8;

  for (int k0 = 0; k0 < K; k0 += 32) {
    __syncthreads();
    async16(&As[t * 8], Ab + (size_t)r0 * K + k0 + kc0);
    async16(&Bs[t * 8], Bb + (size_t)r0 * K + k0 + kc0);
    async16(&As[(256 + t) * 8], Ab + (size_t)(64 + r0) * K + k0 + kc0);
    async16(&Bs[(256 + t) * 8], Bb + (size_t)(64 + r0) * K + k0 + kc0);
    __syncthreads();
    bf16x8 a[4], b[4];
#pragma unroll
    for (int mi = 0; mi < 4; mi++)
      a[mi] = *(const bf16x8*)&As[(wm + mi * 16 + lr) * 32 + lq * 8];
#pragma unroll
    for (int ni = 0; ni < 4; ni++)
      b[ni] = *(const bf16x8*)&Bs[(wn + ni * 16 + lr) * 32 + lq * 8];
#pragma unroll
    for (int mi = 0; mi < 4; mi++)
#pragma unroll
      for (int ni = 0; ni < 4; ni++)
        acc[mi][ni] = mfma16(a[mi], b[ni], acc[mi][ni]);
  }
#pragma unroll
  for (int mi = 0; mi < 4; mi++) {
#pragma unroll
    for (int ni = 0; ni < 4; ni++) {
#pragma unroll
      for (int r = 0; r < 4; r++) {
        int row = m0 + wm + mi * 16 + lq * 4 + r;
        int col = n0 + wn + ni * 16 + lr;
        if (OUT_BF16)
          ((u16*)Cout)[(size_t)row * N + col] = f2bf(acc[mi][ni][r]);
        else
          ((float*)Cout)[(size_t)row * N + col] = acc[mi][ni][r];
      }
    }
  }
}

// --------------------------- flash attention -------------------------------
// Producer-consumer pipeline, 1 barrier/step. Wave w: produces S/P for Q-rows
// [w*16,w*16+16) x 32 j-cols; consumes full P tile (lagged 1 step) against its
// private 64-wide V-strip (V B-frags loaded DIRECT from global, register
// double-buffered; V never in LDS). K staged via DMA (double buffer).
// P + per-wave alpha in double-buffered LDS. l via ones-MFMA on own strip,
// exchanged through LDS at epilogue.

struct FlashCtx {
  const u16* Qbase;
  const u16* Kbase;
  const u16* Vstrip;  // per-wave V column strip base
  int t, w, lr, lq;
};

__device__ __forceinline__ void stage_k(const FlashCtx& cx, int jc, u16* KsN) {
#pragma unroll
  for (int i = 0; i < 2; i++) {
    int q = cx.t + i * 256;
    int row = q >> 4, gp = q & 15;
    int gg = (gp & 8) | ((gp & 7) ^ (row & 7));
    async16(&KsN[q * 8], cx.Kbase + (size_t)(jc + row) * 4096 + gg * 8);
  }
}

__device__ __forceinline__ void load_v(const FlashCtx& cx, int jc, bf16x8* vb) {
#pragma unroll
  for (int et = 0; et < 4; et++)
    vb[et] = *(const bf16x8*)&cx.Vstrip[(size_t)(et * 16 + cx.lr) * 4096 + jc + cx.lq * 8];
}

__device__ __forceinline__ void flash_step(const FlashCtx& cx, const bf16x8* qa,
                                           int j, int nst, int q0,
                                           const u16* KsC, u16* KsN,
                                           const u16* PsR, u16* PsW,
                                           const float* AlR, float* AlW,
                                           const bf16x8* vbU, bf16x8* vbF,
                                           f32x4 acc[4][4], f32x4* lacc,
                                           float* m_, float* aprev) {
  __syncthreads();   // P(j-1)/alpha(j-1) visible; K(j) DMA drained
  int jc = j * 32;
  if (j + 1 < nst) stage_k(cx, jc + 32, KsN);   // K(j+1) in flight during step
  if (j < nst) load_v(cx, jc, vbF);             // V(j) -> regs, used at j+1

  int lr = cx.lr, lq = cx.lq;

  if (j >= 1) {
    // ---- consume: rescale + PV(j-1) + l ----
    f32x4 a4 = *(const f32x4*)AlR;
    if (a4[0] != 1.0f || a4[1] != 1.0f || a4[2] != 1.0f || a4[3] != 1.0f) {
#pragma unroll
      for (int rt = 0; rt < 4; rt++)
#pragma unroll
        for (int et = 0; et < 4; et++)
#pragma unroll
          for (int r = 0; r < 4; r++) acc[rt][et][r] *= a4[rt];
    }
    float aw = *aprev;
    if (aw != 1.0f)
#pragma unroll
      for (int r = 0; r < 4; r++) (*lacc)[r] *= aw;
    bf16x8 pa[4];
#pragma unroll
    for (int rt = 0; rt < 4; rt++)
      pa[rt] = *(const bf16x8*)&PsR[(rt * 16 + lr) * 40 + lq * 8];
#pragma unroll
    for (int rt = 0; rt < 4; rt++)
#pragma unroll
      for (int et = 0; et < 4; et++)
        acc[rt][et] = mfma16(pa[rt], vbU[et], acc[rt][et]);
    const bf16x8 onesb = {0x3F80, 0x3F80, 0x3F80, 0x3F80,
                          0x3F80, 0x3F80, 0x3F80, 0x3F80};
    *lacc = mfma16(pa[cx.w], onesb, *lacc);
  }

  if (j < nst) {
    // ---- produce: S(j) + softmax + P/alpha write ----
    float aj = 1.0f;
    if (jc <= q0 + cx.w * 16 + 15) {
      const float k2 = 0.12753257550036097f;  // log2(e)/sqrt(128)
      f32x4 sacc[2] = {};
#pragma unroll
      for (int ks = 0; ks < 4; ks++) {
#pragma unroll
        for (int ni = 0; ni < 2; ni++) {
          int row = ni * 16 + lr;
          int g = ks * 4 + lq;
          int gp = (g & 8) | ((g & 7) ^ (row & 7));
          bf16x8 kb = *(const bf16x8*)&KsC[row * 128 + gp * 8];
          sacc[ni] = mfma16(qa[ks], kb, sacc[ni]);
        }
      }
      float s2[2][4];
      bool diag = (jc >= q0);
#pragma unroll
      for (int ni = 0; ni < 2; ni++)
#pragma unroll
        for (int r = 0; r < 4; r++) {
          float v = sacc[ni][r] * k2;
          if (diag) {
            int colg = jc + ni * 16 + lr;
            int rowg = q0 + cx.w * 16 + lq * 4 + r;
            if (colg > rowg) v = -INFINITY;
          }
          s2[ni][r] = v;
        }
      float mv = fmaxf(fmaxf(fmaxf(s2[0][0], s2[0][1]), fmaxf(s2[0][2], s2[0][3])),
                       fmaxf(fmaxf(s2[1][0], s2[1][1]), fmaxf(s2[1][2], s2[1][3])));
      mv = fmaxf(mv, __shfl_xor(mv, 1));
      mv = fmaxf(mv, __shfl_xor(mv, 2));
      mv = fmaxf(mv, __shfl_xor(mv, 4));
      mv = fmaxf(mv, __shfl_xor(mv, 8));
      mv = fmaxf(mv, __shfl_xor(mv, 16));
      mv = fmaxf(mv, __shfl_xor(mv, 32));
      float mo = *m_;
      float mn = fmaxf(mo, mv);
      *m_ = mn;
      aj = __builtin_amdgcn_exp2f(mo - mn);
#pragma unroll
      for (int ni = 0; ni < 2; ni++)
#pragma unroll
        for (int r = 0; r < 4; r++) {
          float p = __builtin_amdgcn_exp2f(s2[ni][r] - mn);
          PsW[(cx.w * 16 + lq * 4 + r) * 40 + ni * 16 + lr] =
              (u16)(__float_as_uint(p) >> 16);
        }
    } else {
      // fully-masked strip: publish zeros so consumers add nothing
#pragma unroll
      for (int ni = 0; ni < 2; ni++)
#pragma unroll
        for (int r = 0; r < 4; r++)
          PsW[(cx.w * 16 + lq * 4 + r) * 40 + ni * 16 + lr] = 0;
    }
    if ((cx.t & 63) == 0) AlW[cx.w] = aj;
    *aprev = aj;
  }
}

__global__ __launch_bounds__(256, 2) void flash_diff_kernel(const u16* __restrict__ QKb,
                                                            const u16* __restrict__ Vt,
                                                            u16* __restrict__ o12b) {
  __shared__ __attribute__((aligned(16))) u16 Ks0[32 * 128];
  __shared__ __attribute__((aligned(16))) u16 Ks1[32 * 128];
  __shared__ __attribute__((aligned(16))) u16 Ps0[64 * 40];
  __shared__ __attribute__((aligned(16))) u16 Ps1[64 * 40];
  __shared__ __attribute__((aligned(16))) float Al0[4];
  __shared__ __attribute__((aligned(16))) float Al1[4];
  __shared__ __attribute__((aligned(16))) float lx[64];

  int t = threadIdx.x;
  FlashCtx cx;
  cx.t = t; cx.w = t >> 6;
  cx.lr = t & 15; cx.lq = (t >> 4) & 3;

  // XCD-affine decode: group g=(bh,c) pinned to XCD g&7
  int idx = blockIdx.x;                 // 0..511
  int xcd = idx & 7, slot = idx >> 3;   // slot 0..63
  int pairI = slot & 15, ghi = slot >> 4;
  int g = ghi * 8 + xcd;                // 0..31
  int bh = g >> 1, c = g & 1;
  int b = bh >> 3, h = bh & 7;

  cx.Qbase = QKb + (size_t)b * 2048 * 4096 + h * 256 + c * 128;
  cx.Kbase = cx.Qbase + 2048;
  cx.Vstrip = Vt + (size_t)(h * 256 + cx.w * 64) * 4096 + b * 2048;
  u16* Op = o12b + (size_t)c * (4096ull * 2048) + (size_t)b * 2048 * 2048 + h * 256;

#pragma unroll 1
  for (int phase = 0; phase < 2; phase++) {
    int qi = phase ? (31 - pairI) : pairI;
    int q0 = qi * 64;
    int nst = 2 * qi + 2;   // even

    bf16x8 qa[4];
#pragma unroll
    for (int ks = 0; ks < 4; ks++)
      qa[ks] = *(const bf16x8*)&cx.Qbase[(size_t)(q0 + cx.w * 16 + cx.lr) * 4096 +
                                         ks * 32 + cx.lq * 8];

    f32x4 acc[4][4] = {};
    f32x4 lacc = {};
    bf16x8 vbE[4], vbO[4];
    float m_ = -INFINITY, aprev = 1.0f;

    stage_k(cx, 0, Ks0);   // phase prologue: K(0)

#pragma unroll 1
    for (int jj = 0; jj < nst; jj += 2) {
      flash_step(cx, qa, jj, nst, q0, Ks0, Ks1, Ps1, Ps0, Al1, Al0, vbO, vbE,
                 acc, &lacc, &m_, &aprev);
      flash_step(cx, qa, jj + 1, nst, q0, Ks1, Ks0, Ps0, Ps1, Al0, Al1, vbE, vbO,
                 acc, &lacc, &m_, &aprev);
    }
    // drain: PV(nst-1)  (nst even -> reads Ps1/Al1/vbO)
    flash_step(cx, qa, nst, nst, q0, Ks0, Ks1, Ps1, Ps0, Al1, Al0, vbO, vbE,
               acc, &lacc, &m_, &aprev);

    // epilogue: exchange l, normalize, store
    if (cx.lr == 0) {
#pragma unroll
      for (int r = 0; r < 4; r++) lx[cx.w * 16 + cx.lq * 4 + r] = lacc[r];
    }
    __syncthreads();
#pragma unroll
    for (int rt = 0; rt < 4; rt++) {
      f32x4 lv = *(const f32x4*)&lx[rt * 16 + cx.lq * 4];
#pragma unroll
      for (int r = 0; r < 4; r++) {
        float inv = 1.0f / lv[r];
        int row = q0 + rt * 16 + cx.lq * 4 + r;
#pragma unroll
        for (int et = 0; et < 4; et++)
          Op[(size_t)row * 2048 + cx.w * 64 + et * 16 + cx.lr] =
              f2bf(acc[rt][et][r] * inv);
      }
    }
    __syncthreads();  // lx reads done before next phase reuses it
  }
}

// --------------------------- combine + RMSNorm -----------------------------
__global__ void combine_kernel(const u16* __restrict__ o12b, const float* __restrict__ lamp,
                               const float* __restrict__ g, u16* __restrict__ ob) {
  __shared__ float red[4];
  int t = threadIdx.x;
  int grp = blockIdx.x;  // (b*2048+tt)*8 + h
  size_t idx = (size_t)grp * 256 + t;
  const size_t comp = 4096ull * 2048;
  float lam = lamp[0];
  float v = bf2f(o12b[idx]) - lam * bf2f(o12b[idx + comp]);
  float ss = v * v;
  ss += __shfl_xor(ss, 1);
  ss += __shfl_xor(ss, 2);
  ss += __shfl_xor(ss, 4);
  ss += __shfl_xor(ss, 8);
  ss += __shfl_xor(ss, 16);
  ss += __shfl_xor(ss, 32);
  if ((t & 63) == 0) red[t >> 6] = ss;
  __syncthreads();
  float tot = red[0] + red[1] + red[2] + red[3];
  float scale = rsqrtf(tot * (1.0f / 256.0f) + 1e-5f) * (1.0f - LAMBDA_INIT);
  ob[(size_t)(grp >> 3) * 2048 + (grp & 7) * 256 + t] = f2bf(v * scale * g[t]);
}

// ---------------------------------------------------------------------------

extern "C" void kernel_launch(void* const* d_in, const int* in_sizes, int n_in,
                              void* d_out, int out_size, void* d_ws, size_t ws_size,
                              hipStream_t stream) {
  const float* x   = (const float*)d_in[0];
  const float* Wq  = (const float*)d_in[1];
  const float* Wk  = (const float*)d_in[2];
  const float* Wv  = (const float*)d_in[3];
  const float* Wo  = (const float*)d_in[4];
  const float* lq1 = (const float*)d_in[5];
  const float* lk1 = (const float*)d_in[6];
  const float* lq2 = (const float*)d_in[7];
  const float* lk2 = (const float*)d_in[8];
  const float* g   = (const float*)d_in[9];

  char* ws = (char*)d_ws;
  u16* xb    = (u16*)(ws);
  u16* Wtq   = (u16*)(ws + 16777216);
  u16* Wtk   = (u16*)(ws + 25165824);
  u16* Wtv   = (u16*)(ws + 33554432);
  u16* Wto   = (u16*)(ws + 41943040);
  u16* QKb   = (u16*)(ws + 50331648);
  u16* Vt    = (u16*)(ws + 83886080);
  u16* o12b  = (u16*)(ws + 100663296);
  u16* ob    = (u16*)(ws + 134217728);
  float* lamp = (float*)(ws + 150994944);

  cast_x_kernel<<<8192, 256, 0, stream>>>(x, xb, 2097152);
  transpose_w_kernel<<<dim3(64, 64, 4), dim3(32, 8), 0, stream>>>(
      Wq, Wk, Wv, Wo, Wtq, Wtk, Wtv, Wto);
  lam_kernel<<<1, 64, 0, stream>>>(lq1, lk1, lq2, lk2, lamp);

  // [Q|K] = x @ [Wq|Wk] : M=4096, N=4096 (Wtq,Wtk contiguous)
  gemm_bt_kernel<1><<<dim3(32, 32), 256, 0, stream>>>(xb, Wtq, QKb, 4096, 4096, 2048);
  // V^T directly: C[e][bt] = sum_k Wv[k][e] x[bt][k]  (M=2048, N=4096)
  gemm_bt_kernel<1><<<dim3(32, 16), 256, 0, stream>>>(Wtv, xb, Vt, 2048, 4096, 2048);

  flash_diff_kernel<<<512, 256, 0, stream>>>(QKb, Vt, o12b);
  combine_kernel<<<32768, 256, 0, stream>>>(o12b, lamp, g, ob);
  gemm_bt_kernel<0><<<dim3(16, 32), 256, 0, stream>>>(ob, Wto, (float*)d_out, 4096, 2048, 2048);
}